// Round 1
// baseline (552.667 us; speedup 1.0000x reference)
//
#include <hip/hip_runtime.h>
#include <hip/hip_bf16.h>
#include <math.h>

// Problem constants: B=1, S=2048, DIM=4096, NH=32, NKV=8, HD=128
// qkv width = (32+2*8)*128 = 6144; q cols [0,4096), k cols [4096,5120), v cols [5120,6144)
//
// ROUND 7: qkv GEMM ported to the 256x256 / BK=64 / 8-wave deep-pipelined
// schedule (st_16x32 LDS swizzle, counted vmcnt(6) gates, setprio around MFMA),
// RoPE + V-transpose epilogue kept fused. Out-proj GEMM unchanged (m97 128^2).

typedef __attribute__((ext_vector_type(8))) __bf16 bf16x8;
typedef __attribute__((ext_vector_type(4))) __bf16 bf16x4;
typedef __attribute__((ext_vector_type(4))) float f32x4;

#define NEG_BIG (-1e30f)

#define ASYNC_CP16(gsrc, ldst)                                                            \
  __builtin_amdgcn_global_load_lds((const __attribute__((address_space(1))) void*)(gsrc), \
                                   (__attribute__((address_space(3))) void*)(ldst), 16, 0, 0)

__device__ __forceinline__ f32x4 mfma_bf16(bf16x8 a, bf16x8 b, f32x4 c) {
  return __builtin_amdgcn_mfma_f32_16x16x32_bf16(a, b, c, 0, 0, 0);
}

// fmaxf(NaN, a) = a on AMD (IEEE maxNum) -> clamp also converts NaN to -3e4.
__device__ __forceinline__ float clampf(float v) {
  return fminf(fmaxf(v, -30000.f), 30000.f);
}

__device__ __forceinline__ bf16x8 ldg8(const __hip_bfloat16* p) {
  return *(const bf16x8*)p;
}
__device__ __forceinline__ bf16x8 ldg8(const float* p) {
  f32x4 a = *(const f32x4*)p;
  f32x4 b = *(const f32x4*)(p + 4);
  bf16x8 r;
  r[0] = (__bf16)a[0]; r[1] = (__bf16)a[1]; r[2] = (__bf16)a[2]; r[3] = (__bf16)a[3];
  r[4] = (__bf16)b[0]; r[5] = (__bf16)b[1]; r[6] = (__bf16)b[2]; r[7] = (__bf16)b[3];
  return r;
}

__device__ __forceinline__ void store_c(float* C, size_t idx, float v) {
  C[idx] = clampf(v);
}
__device__ __forceinline__ void store_c(__hip_bfloat16* C, size_t idx, float v) {
  C[idx] = __float2bfloat16(clampf(v));
}

__device__ __forceinline__ void barrier_np() {  // raw barrier, no waitcnt drain
  asm volatile("" ::: "memory");
  __builtin_amdgcn_s_barrier();
  asm volatile("" ::: "memory");
}

// ---------------------------------------------------------------------------
// fp32 -> bf16 bulk convert. 8 elems/thread.
// ---------------------------------------------------------------------------
__global__ __launch_bounds__(256) void cvt_f32_bf16(const float* __restrict__ src,
                                                    __hip_bfloat16* __restrict__ dst) {
  size_t i = ((size_t)blockIdx.x * 256 + threadIdx.x) * 8;
  *(bf16x8*)&dst[i] = ldg8(src + i);
}

// ---------------------------------------------------------------------------
// qkv GEMM, 256x256 tile, BK=64, 512 threads (8 waves, 2Mx4N), 8-phase-style
// schedule with st_16x32 swizzled LDS and counted vmcnt. Fused RoPE +
// V-transpose epilogue. M=2048, N=6144, K=4096 fixed. grid (24, 8).
//
// LDS tile layout (per 256x64 bf16 tile): 16x32 subtiles of 1024B,
// pre-swz byte = (row>>4)*2048 + (col>>5)*1024 + (row&15)*64 + (col&31)*2,
// final byte = pre ^ (((pre>>9)&1)<<5)  [== pre ^ (((row>>3)&1)<<5)].
// Staged LINEARLY by global_load_lds (lane-contiguous dest) from the
// inverse-swizzled global source (rule: swizzle both sides or neither).
//
// Per K-tile: 4 phases x 16 MFMA; phase p computes acc rows {2p,2p+1}.
// Stage units (1 load/thread each): A-slice u = rows {32u..}+{128+32u..},
// B-quarter v = N-rows {64v..}. Slot map: (t,p0)->A3,B3 of t+1 (other buf);
// (t,p1..p3)->A0..A2,B0..B2 of t+2 (same buf; region consumed p-1 phases ago).
// One vmcnt(6) gate at end of each tile => next tile fully landed.
// ---------------------------------------------------------------------------
__global__ __launch_bounds__(512, 2) void gemm_qkv_rope(
    const __hip_bfloat16* __restrict__ A, const __hip_bfloat16* __restrict__ B,
    __hip_bfloat16* __restrict__ qkv, __hip_bfloat16* __restrict__ vt,
    const float* __restrict__ fc) {
  const int NT = 64;  // K/BK = 4096/64
  __shared__ __align__(16) __hip_bfloat16 lds[4][16384];  // 128 KiB
  __hip_bfloat16* const As0 = lds[0];
  __hip_bfloat16* const Bs0 = lds[1];
  __hip_bfloat16* const As1 = lds[2];
  __hip_bfloat16* const Bs1 = lds[3];

  const int tid = threadIdx.x;
  const int lane = tid & 63, wid = tid >> 6;
  const int l15 = lane & 15, quad = lane >> 4;
  const int wr = wid >> 2, wc = wid & 3;  // 2 M-waves x 4 N-waves
  const size_t mBase = (size_t)blockIdx.y * 256, nBase = (size_t)blockIdx.x * 256;

  // ds_read base: col = quad*8 + kk*32, row = <subtile-row>*16 + l15.
  // byte = subrow*2048 + kk*1024 + l15*64 + (quad*16 ^ swzbit)
  const int rdOff = l15 * 64 + ((quad * 16) ^ ((l15 & 8) << 2));
  const int wr8 = wr * 8;   // A subtile-row base (wr*128 >> 4)
  const int wc4 = wc * 4;   // B subtile-row base (wc*64 >> 4)

  // staging source mapping (inverse swizzle of linear LDS slot)
  const char* pAsrc[4];
  const char* pBsrc[4];
  int LAel[4], LBel[4];
#pragma unroll
  for (int u = 0; u < 4; ++u) {
    int LA = (tid < 256) ? (4096 * u + tid * 16) : (16384 + 4096 * u + (tid - 256) * 16);
    int LAs = LA ^ (((LA >> 9) & 1) << 5);
    int stA = LAs >> 10, rA16 = (LAs >> 6) & 15, cbA = LAs & 63;
    int rowA = (stA >> 1) * 16 + rA16;
    int colA = (stA & 1) * 32 + (cbA >> 1);
    pAsrc[u] = (const char*)A + ((mBase + rowA) * (size_t)4096 + colA) * 2;
    LAel[u] = LA >> 1;

    int LB = u * 8192 + tid * 16;
    int LBs = LB ^ (((LB >> 9) & 1) << 5);
    int stB = LBs >> 10, rB16 = (LBs >> 6) & 15, cbB = LBs & 63;
    int rowB = (stB >> 1) * 16 + rB16;
    int colB = (stB & 1) * 32 + (cbB >> 1);
    pBsrc[u] = (const char*)B + ((nBase + rowB) * (size_t)4096 + colB) * 2;
    LBel[u] = LB >> 1;
  }

  f32x4 acc[8][4] = {};

  // prologue: stage tile 0 (8 units) + tile 1 (first 6 units); gate tile 0.
#pragma unroll
  for (int u = 0; u < 4; ++u) {
    ASYNC_CP16(pAsrc[u], As0 + LAel[u]);
    ASYNC_CP16(pBsrc[u], Bs0 + LBel[u]);
  }
#pragma unroll
  for (int u = 0; u < 3; ++u) {
    ASYNC_CP16(pAsrc[u] + 128, As1 + LAel[u]);
    ASYNC_CP16(pBsrc[u] + 128, Bs1 + LBel[u]);
  }
  asm volatile("s_waitcnt vmcnt(6)" ::: "memory");
  barrier_np();

#define QKV_TILE(tt, CA, CB, AA, AB)                                                     \
  {                                                                                      \
    bf16x8 bfr[4][2];                                                                    \
    _Pragma("unroll") for (int p = 0; p < 4; ++p) {                                      \
      bf16x8 afr[2][2];                                                                  \
      _Pragma("unroll") for (int ii = 0; ii < 2; ++ii)                                   \
          _Pragma("unroll") for (int kk = 0; kk < 2; ++kk)                               \
              afr[ii][kk] = *(const bf16x8*)((const char*)(CA) +                         \
                                             ((wr8 + 2 * p + ii) * 2048 + kk * 1024 + rdOff)); \
      if (p == 0) {                                                                      \
        _Pragma("unroll") for (int j = 0; j < 4; ++j)                                    \
            _Pragma("unroll") for (int kk = 0; kk < 2; ++kk)                             \
                bfr[j][kk] = *(const bf16x8*)((const char*)(CB) +                        \
                                              ((wc4 + j) * 2048 + kk * 1024 + rdOff));   \
        if ((tt) + 1 < NT) {                                                             \
          ASYNC_CP16(pAsrc[3] + ((tt) + 1) * 128, (AA) + LAel[3]);                       \
          ASYNC_CP16(pBsrc[3] + ((tt) + 1) * 128, (AB) + LBel[3]);                       \
        }                                                                                \
      } else if ((tt) + 2 < NT) {                                                        \
        ASYNC_CP16(pAsrc[p - 1] + ((tt) + 2) * 128, (CA) + LAel[p - 1]);                 \
        ASYNC_CP16(pBsrc[p - 1] + ((tt) + 2) * 128, (CB) + LBel[p - 1]);                 \
      }                                                                                  \
      barrier_np();                                                                      \
      asm volatile("s_waitcnt lgkmcnt(0)" ::: "memory");                                 \
      __builtin_amdgcn_sched_barrier(0);                                                 \
      __builtin_amdgcn_s_setprio(1);                                                     \
      _Pragma("unroll") for (int ii = 0; ii < 2; ++ii)                                   \
          _Pragma("unroll") for (int j = 0; j < 4; ++j)                                  \
              _Pragma("unroll") for (int kk = 0; kk < 2; ++kk)                           \
                  acc[2 * p + ii][j] = mfma_bf16(afr[ii][kk], bfr[j][kk], acc[2 * p + ii][j]); \
      __builtin_amdgcn_s_setprio(0);                                                     \
      if (p == 3) {                                                                      \
        if ((tt) < NT - 2) {                                                             \
          asm volatile("s_waitcnt vmcnt(6)" ::: "memory");                               \
        } else if ((tt) == NT - 2) {                                                     \
          asm volatile("s_waitcnt vmcnt(0)" ::: "memory");                               \
        }                                                                                \
      }                                                                                  \
      barrier_np();                                                                      \
    }                                                                                    \
  }

  for (int t2 = 0; t2 < NT; t2 += 2) {
    QKV_TILE(t2, As0, Bs0, As1, Bs1);
    QKV_TILE(t2 + 1, As1, Bs1, As0, Bs0);
  }
#undef QKV_TILE

  // fused epilogue. c < 5120 is block-uniform (nBase multiple of 256, 5120%256==0).
#pragma unroll
  for (int i = 0; i < 8; ++i)
#pragma unroll
    for (int j = 0; j < 4; ++j) {
      size_t c = nBase + wc * 64 + j * 16 + l15;        // C/D: col=lane&15
      size_t srow0 = mBase + wr * 128 + i * 16 + quad * 4;  // C/D: row=(lane>>4)*4+r
      if (c < 5120) {
        int di2 = (int)(c & 126);  // 2*(pair index within head)
#pragma unroll
        for (int r = 0; r < 4; r++) {
          float v = clampf(acc[i][j][r]);
          float vp = __shfl_xor(v, 1);  // pair-column partner (adjacent lane)
          size_t s = srow0 + r;
          float cs = fc[s * 128 + di2];
          float sn = fc[s * 128 + di2 + 1];
          float ov = ((c & 1) == 0) ? (v * cs - vp * sn) : (vp * sn + v * cs);
          qkv[s * 6144 + c] = __float2bfloat16(ov);
        }
      } else {
        bf16x4 pk;
#pragma unroll
        for (int r = 0; r < 4; r++) pk[r] = (__bf16)clampf(acc[i][j][r]);
        *(bf16x4*)&vt[(c - 5120) * 2048 + srow0] = pk;  // 8B packed, rows contiguous
      }
    }
}

// ---------------------------------------------------------------------------
// NT GEMM, m97 structure (fast path, out-proj): bf16 in, fp32/bf16 out.
// ---------------------------------------------------------------------------
template <typename TC>
__global__ __launch_bounds__(256) void gemm_nt_async(
    const __hip_bfloat16* __restrict__ A, const __hip_bfloat16* __restrict__ B,
    TC* __restrict__ C, int M, int N, int K) {
  __shared__ __align__(16) __hip_bfloat16 As[128 * 32];
  __shared__ __align__(16) __hip_bfloat16 Bs[128 * 32];
  const int tid = threadIdx.x;
  const int lane = tid & 63, wave = tid >> 6;
  const int l15 = lane & 15, quad = lane >> 4;
  const int wm = (wave >> 1) * 64, wn = (wave & 1) * 64;
  const size_t mBase = (size_t)blockIdx.y * 128, nBase = (size_t)blockIdx.x * 128;

  const int ldRow = tid >> 2;
  const int ldCol = (tid & 3) * 8;
  const __hip_bfloat16* Ap = A + (mBase + ldRow) * (size_t)K + ldCol;
  const __hip_bfloat16* Bp = B + (nBase + ldRow) * (size_t)K + ldCol;

  f32x4 acc[4][4] = {};

  for (int k0 = 0; k0 < K; k0 += 32) {
    ASYNC_CP16(Ap, &As[tid * 8]);
    ASYNC_CP16(Ap + (size_t)64 * K, &As[2048 + tid * 8]);
    ASYNC_CP16(Bp, &Bs[tid * 8]);
    ASYNC_CP16(Bp + (size_t)64 * K, &Bs[2048 + tid * 8]);
    Ap += 32; Bp += 32;
    __syncthreads();
    bf16x8 af[4], bfr[4];
#pragma unroll
    for (int i = 0; i < 4; i++)
      af[i] = *(const bf16x8*)&As[(wm + i * 16 + l15) * 32 + quad * 8];
#pragma unroll
    for (int j = 0; j < 4; j++)
      bfr[j] = *(const bf16x8*)&Bs[(wn + j * 16 + l15) * 32 + quad * 8];
#pragma unroll
    for (int i = 0; i < 4; i++)
#pragma unroll
      for (int j = 0; j < 4; j++)
        acc[i][j] = mfma_bf16(af[i], bfr[j], acc[i][j]);
    __syncthreads();
  }

#pragma unroll
  for (int i = 0; i < 4; i++)
#pragma unroll
    for (int j = 0; j < 4; j++)
#pragma unroll
      for (int r = 0; r < 4; r++) {
        size_t row = mBase + wm + i * 16 + quad * 4 + r;
        size_t col = nBase + wn + j * 16 + l15;
        store_c(C, row * (size_t)N + col, acc[i][j][r]);
      }
}

// ---------------------------------------------------------------------------
// Fallback path kernels (ws too small for bf16 weight buffers).
// ---------------------------------------------------------------------------
template <typename TA, typename TB, typename TC>
__global__ __launch_bounds__(256) void gemm_nt(
    const TA* __restrict__ A, const TB* __restrict__ B,
    TC* __restrict__ C, int M, int N, int K) {
  __shared__ __align__(16) __hip_bfloat16 As[128 * 32];
  __shared__ __align__(16) __hip_bfloat16 Bs[128 * 32];
  const int tid = threadIdx.x;
  const int lane = tid & 63, wave = tid >> 6;
  const int l15 = lane & 15, quad = lane >> 4;
  const int wm = (wave >> 1) * 64, wn = (wave & 1) * 64;
  const size_t mBase = (size_t)blockIdx.y * 128, nBase = (size_t)blockIdx.x * 128;
  const int ldRow = tid >> 2;
  const int ldCol = (tid & 3) * 8;
  const TA* Ap = A + (mBase + ldRow) * (size_t)K + ldCol;
  const TB* Bp = B + (nBase + ldRow) * (size_t)K + ldCol;
  f32x4 acc[4][4] = {};
  for (int k0 = 0; k0 < K; k0 += 32) {
    bf16x8 a0 = ldg8(Ap);
    bf16x8 a1 = ldg8(Ap + (size_t)64 * K);
    bf16x8 b0 = ldg8(Bp);
    bf16x8 b1 = ldg8(Bp + (size_t)64 * K);
    Ap += 32; Bp += 32;
    *(bf16x8*)&As[tid * 8] = a0;
    *(bf16x8*)&As[2048 + tid * 8] = a1;
    *(bf16x8*)&Bs[tid * 8] = b0;
    *(bf16x8*)&Bs[2048 + tid * 8] = b1;
    __syncthreads();
    bf16x8 af[4], bfr[4];
#pragma unroll
    for (int i = 0; i < 4; i++)
      af[i] = *(const bf16x8*)&As[(wm + i * 16 + l15) * 32 + quad * 8];
#pragma unroll
    for (int j = 0; j < 4; j++)
      bfr[j] = *(const bf16x8*)&Bs[(wn + j * 16 + l15) * 32 + quad * 8];
#pragma unroll
    for (int i = 0; i < 4; i++)
#pragma unroll
      for (int j = 0; j < 4; j++)
        acc[i][j] = mfma_bf16(af[i], bfr[j], acc[i][j]);
    __syncthreads();
  }
#pragma unroll
  for (int i = 0; i < 4; i++)
#pragma unroll
    for (int j = 0; j < 4; j++)
#pragma unroll
      for (int r = 0; r < 4; r++) {
        size_t row = mBase + wm + i * 16 + quad * 4 + r;
        size_t col = nBase + wn + j * 16 + l15;
        store_c(C, row * (size_t)N + col, acc[i][j][r]);
      }
}

__global__ __launch_bounds__(256) void rope_kernel(__hip_bfloat16* __restrict__ qkv,
                                                   const float* __restrict__ fc) {
  int idx = blockIdx.x * 256 + threadIdx.x;
  int d = idx & 63;
  int h = (idx >> 6) % 40;
  int s = idx / (40 * 64);
  size_t off = (size_t)s * 6144 + h * 128 + d * 2;
  float x0 = __bfloat162float(qkv[off]);
  float x1 = __bfloat162float(qkv[off + 1]);
  float c = fc[s * 128 + d * 2];
  float sn = fc[s * 128 + d * 2 + 1];
  qkv[off] = __float2bfloat16(x0 * c - x1 * sn);
  qkv[off + 1] = __float2bfloat16(x0 * sn + x1 * c);
}

__global__ __launch_bounds__(256) void transpose_v(const __hip_bfloat16* __restrict__ qkv,
                                                   __hip_bfloat16* __restrict__ vt) {
  __shared__ __hip_bfloat16 tile[32][33];
  int x = threadIdx.x & 31, y = threadIdx.x >> 5;
  int colBase = blockIdx.x * 32;
  int sBase = blockIdx.y * 32;
#pragma unroll
  for (int i = 0; i < 4; i++)
    tile[y + i * 8][x] = qkv[(size_t)(sBase + y + i * 8) * 6144 + 5120 + colBase + x];
  __syncthreads();
#pragma unroll
  for (int i = 0; i < 4; i++)
    vt[(size_t)(colBase + y + i * 8) * 2048 + sBase + x] = tile[x][y + i * 8];
}

// ---------------------------------------------------------------------------
// Flash attention, causal GQA. BQ=128: grid = (NH, S/128), qt reversed so
// diagonal-heavy blocks dispatch first. 4 waves x 32 q-rows (two 16-row
// A-frags -> K-fragment LDS reads reused 2x). K/Vt staged via global_load_lds
// with source-side XOR-chunk swizzle; Ps (16 rows/wave) reused for t=0,1
// (wave-private DS is in-order).
// ---------------------------------------------------------------------------
__global__ __launch_bounds__(256) void flash_attn(
    const __hip_bfloat16* __restrict__ qkv, const __hip_bfloat16* __restrict__ vt,
    __hip_bfloat16* __restrict__ o) {
  __shared__ __align__(16) __hip_bfloat16 Ks[64 * 128];
  __shared__ __align__(16) __hip_bfloat16 Vs[128 * 64];
  __shared__ __align__(16) __hip_bfloat16 Ps[4][16 * 72];
  const int tid = threadIdx.x;
  const int lane = tid & 63, wave = tid >> 6;
  const int l15 = lane & 15, quad = lane >> 4;
  const int h = blockIdx.x, g = h >> 2;        // GQA: kv head = h/4
  const int qt = 15 - blockIdx.y;              // big blocks first
  const int qBase = qt * 128;
  const int qRowW = qBase + wave * 32;         // this wave's 32 q-rows

  bf16x8 qf[2][4];
#pragma unroll
  for (int t = 0; t < 2; t++) {
    const __hip_bfloat16* qp =
        qkv + (size_t)(qRowW + t * 16 + l15) * 6144 + h * 128 + quad * 8;
#pragma unroll
    for (int d = 0; d < 4; d++) qf[t][d] = *(const bf16x8*)(qp + d * 32);
  }

  f32x4 acc_o[2][8] = {};
  float m_i[2][4], l_i[2][4];
#pragma unroll
  for (int t = 0; t < 2; t++)
#pragma unroll
    for (int r = 0; r < 4; r++) { m_i[t][r] = NEG_BIG; l_i[t][r] = 0.f; }

  const float scale = 0.08838834764831845f;  // 1/sqrt(128)
  const int nkt = 2 * qt + 2;
  for (int kt = 0; kt < nkt; kt++) {
    const int kBase = kt * 64;
    // stage K tile [64 rows][16 slots]: slot chl holds global chunk chl^(row&15)
#pragma unroll
    for (int rnd = 0; rnd < 4; rnd++) {
      int ci = rnd * 256 + tid;
      int row = ci >> 4, chl = ci & 15;
      int chg = chl ^ (row & 15);
      ASYNC_CP16(qkv + (size_t)(kBase + row) * 6144 + 4096 + g * 128 + chg * 8, &Ks[ci * 8]);
    }
    // stage Vt tile [128 rows(n)][8 slots]: slot chl holds global chunk chl^(n&7)
#pragma unroll
    for (int rnd = 0; rnd < 4; rnd++) {
      int ci = rnd * 256 + tid;
      int n = ci >> 3, chl = ci & 7;
      int chg = chl ^ (n & 7);
      ASYNC_CP16(vt + (size_t)(g * 128 + n) * 2048 + kBase + chg * 8, &Vs[ci * 8]);
    }
    __syncthreads();

    // S = Q K^T for both q-tiles; kb read once per (d,j), used twice
    f32x4 sc[2][4] = {};
#pragma unroll
    for (int d = 0; d < 4; d++) {
#pragma unroll
      for (int j = 0; j < 4; j++) {
        bf16x8 kb = *(const bf16x8*)&Ks[(j * 16 + l15) * 128 + ((d * 4 + quad) ^ l15) * 8];
        sc[0][j] = mfma_bf16(qf[0][d], kb, sc[0][j]);
        sc[1][j] = mfma_bf16(qf[1][d], kb, sc[1][j]);
      }
    }

#pragma unroll
    for (int t = 0; t < 2; t++) {
      const int qRowT = qRowW + t * 16;
      float rowmax[4] = {NEG_BIG, NEG_BIG, NEG_BIG, NEG_BIG};
      float sv[4][4];
#pragma unroll
      for (int j = 0; j < 4; j++) {
        int kcol = kBase + j * 16 + l15;
#pragma unroll
        for (int r = 0; r < 4; r++) {
          float s = clampf(sc[t][j][r] * scale);
          if (kcol > qRowT + quad * 4 + r) s = NEG_BIG;
          sv[j][r] = s;
          rowmax[r] = fmaxf(rowmax[r], s);
        }
      }
#pragma unroll
      for (int off = 8; off; off >>= 1)
#pragma unroll
        for (int r = 0; r < 4; r++)
          rowmax[r] = fmaxf(rowmax[r], __shfl_xor(rowmax[r], off, 16));

      float alpha[4], rowsum[4];
#pragma unroll
      for (int r = 0; r < 4; r++) {
        float mnew = fmaxf(m_i[t][r], rowmax[r]);
        alpha[r] = __expf(m_i[t][r] - mnew);
        m_i[t][r] = mnew;
        rowsum[r] = 0.f;
      }
#pragma unroll
      for (int j = 0; j < 4; j++)
#pragma unroll
        for (int r = 0; r < 4; r++) {
          float p = __expf(sv[j][r] - m_i[t][r]);
          rowsum[r] += p;
          Ps[wave][(quad * 4 + r) * 72 + j * 16 + l15] = __float2bfloat16(p);
        }
#pragma unroll
      for (int off = 8; off; off >>= 1)
#pragma unroll
        for (int r = 0; r < 4; r++)
          rowsum[r] += __shfl_xor(rowsum[r], off, 16);
#pragma unroll
      for (int r = 0; r < 4; r++) l_i[t][r] = l_i[t][r] * alpha[r] + rowsum[r];

#pragma unroll
      for (int jt = 0; jt < 8; jt++)
#pragma unroll
        for (int r = 0; r < 4; r++) acc_o[t][jt][r] *= alpha[r];

      // O += P V (wave-private Ps write->read: DS in-order, no barrier)
#pragma unroll
      for (int kk = 0; kk < 2; kk++) {
        bf16x8 pa = *(const bf16x8*)&Ps[wave][l15 * 72 + kk * 32 + quad * 8];
#pragma unroll
        for (int jt = 0; jt < 8; jt++) {
          int n = jt * 16 + l15;
          bf16x8 vb = *(const bf16x8*)&Vs[n * 64 + (((kk * 4 + quad) ^ (n & 7))) * 8];
          acc_o[t][jt] = mfma_bf16(pa, vb, acc_o[t][jt]);
        }
      }
    }
    __syncthreads();  // protect Ks/Vs from next tile's staging
  }

#pragma unroll
  for (int t = 0; t < 2; t++)
#pragma unroll
    for (int r = 0; r < 4; r++) {
      float inv = 1.f / l_i[t][r];
      size_t qr = qRowW + t * 16 + quad * 4 + r;
#pragma unroll
      for (int jt = 0; jt < 8; jt++)
        o[qr * 4096 + h * 128 + jt * 16 + l15] =
            __float2bfloat16(clampf(acc_o[t][jt][r] * inv));
    }
}

// ---------------------------------------------------------------------------
extern "C" void kernel_launch(void* const* d_in, const int* in_sizes, int n_in,
                              void* d_out, int out_size, void* d_ws, size_t ws_size,
                              hipStream_t stream) {
  const float* x = (const float*)d_in[0];     // [2048][4096] fp32
  const float* fc = (const float*)d_in[1];    // [2048][64][2] fp32
  const float* wqkv = (const float*)d_in[2];  // [6144][4096] fp32
  const float* wo = (const float*)d_in[3];    // [4096][4096] fp32
  float* out = (float*)d_out;                 // [2048][4096] fp32

  char* ws = (char*)d_ws;
  __hip_bfloat16* qkv = (__hip_bfloat16*)ws;                        // 25,165,824 B
  __hip_bfloat16* vt  = (__hip_bfloat16*)(ws + 25165824);           //  4,194,304 B
  __hip_bfloat16* ob  = (__hip_bfloat16*)(ws + 29360128);           // 16,777,216 B
  __hip_bfloat16* xb  = (__hip_bfloat16*)(ws + 46137344);           // 16,777,216 B
  __hip_bfloat16* wb  = (__hip_bfloat16*)(ws + 62914560);           // 50,331,648 B -> end 113,246,208

  const bool fast = ws_size >= (size_t)113246208;  // constant across calls: graph-safe

  if (fast) {
    cvt_f32_bf16<<<dim3(4096), 256, 0, stream>>>(x, xb);      //  8.4M elems
    cvt_f32_bf16<<<dim3(12288), 256, 0, stream>>>(wqkv, wb);  // 25.2M elems
    gemm_qkv_rope<<<dim3(24, 8), 512, 0, stream>>>(xb, wb, qkv, vt, fc);
  } else {
    gemm_nt<float, float, __hip_bfloat16>
        <<<dim3(48, 16), 256, 0, stream>>>(x, wqkv, qkv, 2048, 6144, 4096);
    rope_kernel<<<dim3(20480), 256, 0, stream>>>(qkv, fc);
    transpose_v<<<dim3(32, 64), 256, 0, stream>>>(qkv, vt);
  }
  flash_attn<<<dim3(32, 16), 256, 0, stream>>>(qkv, vt, ob);
  if (fast) {
    cvt_f32_bf16<<<dim3(8192), 256, 0, stream>>>(wo, wb);     // 16.8M elems (reuse wb)
    gemm_nt_async<float>
        <<<dim3(32, 16), 256, 0, stream>>>(ob, wb, out, 2048, 4096, 4096);
  } else {
    gemm_nt<__hip_bfloat16, float, float>
        <<<dim3(32, 16), 256, 0, stream>>>(ob, wo, out, 2048, 4096, 4096);
  }
}